// Round 18
// baseline (1259.192 us; speedup 1.0000x reference)
//
#include <hip/hip_runtime.h>
#include <stdint.h>

// W8A16 GEMM: out[m,n] = s[n] * sum_k a[m,k] * q_int8[k,n] + bias[n]
// M=8192, N=16384, K=4096. Harness dtypes: A,S,Bias f32; Q int32; OUT f32.
//
// Round 18: R17 (32x32x16 MFMA) + conflict-free LDS layout [kq][row][c2].
// 32-row frag reads made each 8-lane group hit bank = f(chunk) only ->
// 1.007e8 conflicts. New layout: elem = kq*8192 + row*32 + c2*8, read
// c2 = ks ^ ((l31>>1)&3) -> 8 consecutive lanes cover all 32 banks.
// Staging stays gload_lds-linear; source pointers inverse-permuted
// (rl=tid>>2, c2=tid&3, ksel=c2^((rl>>1)&3)); dest offsets unchanged ->
// identical vmcnt accounting. All else R17-exact (refcheck-verified).

typedef __bf16 bf16x8 __attribute__((ext_vector_type(8)));
typedef float  f32x4  __attribute__((ext_vector_type(4)));
typedef float  f32x16 __attribute__((ext_vector_type(16)));

#define M_TOT 8192
#define N_TOT 16384
#define K_TOT 4096
#define BM 256
#define BN 256
#define BK 64
#define NT (K_TOT / BK)        // 64 K-tiles (even -> clean 2x unroll)
#define SLOT_ELEMS 16384       // 2 kq * 256 rows * 4 c2 * 8 elems = 32 KB

__device__ __forceinline__ void gload_lds16(const void* g, void* l) {
  __builtin_amdgcn_global_load_lds(
      (const __attribute__((address_space(1))) unsigned int*)g,
      (__attribute__((address_space(3))) unsigned int*)l,
      16, 0, 0);
}

// ---------- merged pre-pass: blocks [0,16384) cvt A; [16384,32768) transpose Q
__global__ void __launch_bounds__(256)
prep_kernel(const float* __restrict__ A, __bf16* __restrict__ Abf,
            const int* __restrict__ Q, __bf16* __restrict__ Bt) {
  __shared__ __bf16 t[64][72];   // 16B-aligned rows; reads 2-way (free)
  const int tid = threadIdx.x;
  if (blockIdx.x < 16384) {
    const size_t i = ((size_t)blockIdx.x * 256 + tid) * 8;
    f32x4 lo = *(const f32x4*)(A + i);
    f32x4 hi = *(const f32x4*)(A + i + 4);
    bf16x8 v;
    #pragma unroll
    for (int j = 0; j < 4; ++j) {
      v[j]     = (__bf16)lo[j];
      v[j + 4] = (__bf16)hi[j];
    }
    *(bf16x8*)(Abf + i) = v;
  } else {
    const int bid = blockIdx.x - 16384;
    const int bk = bid & 63;
    const int bn = bid >> 6;
    const int k0 = bk * 64, n0 = bn * 64;
    const int tx = tid & 63;
    const int ty = tid >> 6;
    const int kb = ty * 16;
    int q[16];
    #pragma unroll
    for (int i = 0; i < 16; ++i)
      q[i] = Q[(size_t)(k0 + kb + i) * N_TOT + n0 + tx];
    bf16x8 v0, v1;
    #pragma unroll
    for (int i = 0; i < 8; ++i) {
      v0[i] = (__bf16)(float)q[i];
      v1[i] = (__bf16)(float)q[i + 8];
    }
    *(bf16x8*)&t[tx][kb]     = v0;
    *(bf16x8*)&t[tx][kb + 8] = v1;
    __syncthreads();
    const int nrow = tid >> 2;
    const int kc   = (tid & 3) * 16;
    bf16x8 w0 = *(const bf16x8*)&t[nrow][kc];
    bf16x8 w1 = *(const bf16x8*)&t[nrow][kc + 8];
    __bf16* dst = Bt + (size_t)(n0 + nrow) * K_TOT + k0 + kc;
    *(bf16x8*)(dst)     = w0;
    *(bf16x8*)(dst + 8) = w1;
  }
}

// --- main GEMM: 256^2 / BK=64 / A3+B2 ring / 32x32 MFMA / [kq][row][c2] --
__global__ void __launch_bounds__(512, 2)
w8a16_gemm_ws(const __bf16* __restrict__ A,   // [M,K] bf16
              const __bf16* __restrict__ Bt,  // [N,K] bf16
              const float*  __restrict__ S,
              const float*  __restrict__ Bias,
              float*        __restrict__ O)
{
  extern __shared__ __bf16 lds[];
  __bf16* const aBase = lds;                     // A: 3 slots of 32 KB
  __bf16* const bBase = lds + 3 * SLOT_ELEMS;    // B: 2 slots of 32 KB

  const int tid  = threadIdx.x;
  const int lane = tid & 63;
  const int wv   = tid >> 6;     // 0..7
  const int wm   = wv >> 2;      // 0..1 : M-wave (rows wm*128)
  const int wn   = wv & 3;       // 0..3 : N-wave (cols wn*64)
  const int rot  = (wv >> 2) << 1;   // m-frag rotation (SIMD-mates 2 apart)

  // XCD map: xcd owns 8 bx-columns; by fastest (B-panel L2-resident).
  const int bid = blockIdx.x;
  const int xcd = bid & 7;
  const int c   = bid >> 3;                 // [0,256)
  const int bx  = xcd * 8 + (c >> 5);       // [0,64)
  const int by  = c & 31;                   // [0,32)
  const int m0  = by * BM;
  const int n0  = bx * BN;

  // ---- staging geometry for [kq][row][c2] layout ----
  // chunk L = j*512 + tid holds (kq=L>>10, rloc=(L>>2)&255, c2=L&3);
  // global k-chunk ks = c2 ^ ((rloc>>1)&3); k-elem = ks*16 + kq*8.
  // dest elem offset = L*8 -> same dA/+4096/+8192/+12288 as before.
  const int rl   = tid >> 2;                       // 0..127
  const int c2s  = tid & 3;
  const int ksel = c2s ^ ((rl >> 1) & 3);
  const __bf16* pa0 = A  + (size_t)(m0 + rl)       * K_TOT + ksel * 16;
  const __bf16* pa1 = A  + (size_t)(m0 + 128 + rl) * K_TOT + ksel * 16;
  const __bf16* pa2 = pa0 + 8;   // kq=1 half of same row
  const __bf16* pa3 = pa1 + 8;
  const __bf16* pb0 = Bt + (size_t)(n0 + rl)       * K_TOT + ksel * 16;
  const __bf16* pb1 = Bt + (size_t)(n0 + 128 + rl) * K_TOT + ksel * 16;
  const __bf16* pb2 = pb0 + 8;
  const __bf16* pb3 = pb1 + 8;
  const int dA = tid * 8;

#define STAGE_A(dst) do {                                  \
    gload_lds16(pa0, (dst) + dA);                          \
    gload_lds16(pa1, (dst) + 4096  + dA);                  \
    gload_lds16(pa2, (dst) + 8192  + dA);                  \
    gload_lds16(pa3, (dst) + 12288 + dA);                  \
    pa0 += BK; pa1 += BK; pa2 += BK; pa3 += BK;            \
  } while (0)
#define STAGE_B(dst) do {                                  \
    gload_lds16(pb0, (dst) + dA);                          \
    gload_lds16(pb1, (dst) + 4096  + dA);                  \
    gload_lds16(pb2, (dst) + 8192  + dA);                  \
    gload_lds16(pb3, (dst) + 12288 + dA);                  \
  } while (0)
#define ADV_B() do { pb0 += BK; pb1 += BK; pb2 += BK; pb3 += BK; } while (0)

  // ---- fragment-read constants (32x32x16, [kq][row][c2] layout) ----
  // lane l: row = base + l31, k-half kq = l>>5; logical k-chunk ks ->
  // c2 = ks ^ sL, sL = (l31>>1)&3 (bases are multiples of 32 -> drop out).
  // elem = kq*8192 + row*32 + c2*8.
  const int l31 = lane & 31;
  const int kq  = lane >> 5;
  const int sL  = (l31 >> 1) & 3;
  const int aRowOff = kq * 8192 + (wm * 128 + l31) * 32;  // + qq*1024
  const int bRowOff = kq * 8192 + (wn * 64  + l31) * 32;  // + ni*1024

  f32x16 acc[4][2];   // acc[pp][ni] <-> m-frag (pp+rot)&3, n-frag ni
  #pragma unroll
  for (int i = 0; i < 4; ++i)
    #pragma unroll
    for (int j = 0; j < 2; ++j)
      #pragma unroll
      for (int r = 0; r < 16; ++r)
        acc[i][j][r] = 0.f;

  bf16x8 b0[2][4], b1[2][4];   // B frag double-buffer [ni][ks]

  // ---- prologue: A(0)->s0, B(0)->bs0, B(1)->bs1, A(1)->s1 ----
  STAGE_A(aBase);
  STAGE_B(bBase);              ADV_B();
  STAGE_B(bBase + SLOT_ELEMS); ADV_B();
  STAGE_A(aBase + SLOT_ELEMS);
  asm volatile("s_waitcnt vmcnt(4)" ::: "memory");
  __builtin_amdgcn_s_barrier();

  // peel: B(0) frags -> b0
  #pragma unroll
  for (int ni = 0; ni < 2; ++ni)
    #pragma unroll
    for (int ks = 0; ks < 4; ++ks)
      b0[ni][ks] = *(const bf16x8*)(
          bBase + bRowOff + ni * 1024 + ((ks ^ sL)) * 8);
  asm volatile("s_waitcnt lgkmcnt(0)" ::: "memory");
  __builtin_amdgcn_s_barrier();

  int csA = 0;
  int nsA = 2;

  // TILE body: BCUR = frags of B(t), BNXT <- frags of B(t+1) (2 per phase).
#define TILE_BODY(t, BCUR, BNXT, bStageLds, bReadLds) do {                  \
    if ((t) < NT - 1) { asm volatile("s_waitcnt vmcnt(4)" ::: "memory"); }  \
    else              { asm volatile("s_waitcnt vmcnt(0)" ::: "memory"); }  \
    asm volatile("s_waitcnt lgkmcnt(0)" ::: "memory");                      \
    __builtin_amdgcn_s_barrier();                                           \
    const __bf16* const aC_ = aBase + csA * SLOT_ELEMS;                     \
    __bf16* const aN_ = aBase + nsA * SLOT_ELEMS;                           \
    _Pragma("unroll")                                                       \
    for (int pp = 0; pp < 4; ++pp) {                                        \
      const int qq = (pp + rot) & 3;                                        \
      const __bf16* aQ = aC_ + aRowOff + qq * 1024;                         \
      bf16x8 aA[4];                                                         \
      _Pragma("unroll")                                                     \
      for (int ks = 0; ks < 4; ++ks)                                        \
        aA[ks] = *(const bf16x8*)(aQ + ((ks ^ sL)) * 8);                    \
      if ((t) + 1 < NT) {                                                   \
        const int ni_ = pp >> 1;                                            \
        const int ks_ = (pp & 1) << 1;                                      \
        BNXT[ni_][ks_] = *(const bf16x8*)(                                  \
            (bReadLds) + bRowOff + ni_ * 1024 + ((ks_ ^ sL)) * 8);          \
        BNXT[ni_][ks_ + 1] = *(const bf16x8*)(                              \
            (bReadLds) + bRowOff + ni_ * 1024 + (((ks_ + 1) ^ sL)) * 8);    \
      }                                                                     \
      if (pp == 0 && (t) + 2 < NT) { STAGE_B(bStageLds); ADV_B(); }         \
      if (pp == 1 && (t) + 2 < NT) STAGE_A(aN_);                            \
      __builtin_amdgcn_s_setprio(1);                                        \
      _Pragma("unroll")                                                     \
      for (int ni = 0; ni < 2; ++ni)                                        \
        _Pragma("unroll")                                                   \
        for (int ks = 0; ks < 4; ++ks)                                      \
          acc[pp][ni] = __builtin_amdgcn_mfma_f32_32x32x16_bf16(            \
              aA[ks], BCUR[ni][ks], acc[pp][ni], 0, 0, 0);                  \
      __builtin_amdgcn_s_setprio(0);                                        \
    }                                                                       \
    csA = (csA == 2) ? 0 : csA + 1;                                         \
    nsA = (nsA == 2) ? 0 : nsA + 1;                                         \
  } while (0)

  for (int tt = 0; tt < NT; tt += 2) {
    TILE_BODY(tt,     b0, b1, bBase,              bBase + SLOT_ELEMS);
    TILE_BODY(tt + 1, b1, b0, bBase + SLOT_ELEMS, bBase);
  }
#undef TILE_BODY
#undef STAGE_A
#undef STAGE_B
#undef ADV_B

  // ---- epilogue: scale+bias, f32 stores (R17-verified 32x32 C/D map) ----
  // col = lane&31, row = (reg&3) + 8*(reg>>2) + 4*(lane>>5), reg in [0,16).
  #pragma unroll
  for (int pp = 0; pp < 4; ++pp) {
    const int qq = (pp + rot) & 3;
    const int rowq = m0 + wm * 128 + qq * 32 + kq * 4;
    #pragma unroll
    for (int ni = 0; ni < 2; ++ni) {
      const int col = n0 + wn * 64 + ni * 32 + l31;
      const float sc = S[col];
      const float bb = Bias[col];
      #pragma unroll
      for (int reg = 0; reg < 16; ++reg) {
        const int row = rowq + (reg & 3) + ((reg >> 2) << 3);
        O[(size_t)row * N_TOT + col] = acc[pp][ni][reg] * sc + bb;
      }
    }
  }
}

// ---------------- fallback: fused kernel (ws too small) ----------------
#define FBM 128
#define FBN 128
#define FBK 32
#define BSTRIDE 40
__device__ __forceinline__ int swz_s(int row) {
  return (row & 3) ^ ((row >> 2) & 1);
}
__global__ void __launch_bounds__(256)
w8a16_gemm_fused(const float* __restrict__ A, const int* __restrict__ Q,
                 const float* __restrict__ S, const float* __restrict__ Bias,
                 float* __restrict__ O)
{
  __shared__ __bf16 a_lds[FBM * FBK];
  __shared__ __bf16 b_lds[FBN * BSTRIDE];
  const int tid = threadIdx.x, lane = tid & 63, wv = tid >> 6;
  const int bid = blockIdx.x;
  const int swz = (bid & 7) * 1024 + (bid >> 3);
  const int bx = swz >> 6, by = swz & 63;
  const int m0 = by * FBM, n0 = bx * FBN;
  const int mA0 = tid >> 2, mA1 = (256 + tid) >> 2;
  const int kcA = tid & 3;
  const int kp0 = kcA ^ swz_s(mA0), kp1 = kcA ^ swz_s(mA1);
  const float* pA0 = A + (size_t)(m0 + mA0) * K_TOT + kcA * 8;
  const float* pA1 = A + (size_t)(m0 + mA1) * K_TOT + kcA * 8;
  __bf16* dA0 = a_lds + mA0 * FBK + kp0 * 8;
  __bf16* dA1 = a_lds + mA1 * FBK + kp1 * 8;
  const int nB = tid & 127, kg = (tid >> 7) * 16;
  const int* pQ = Q + (size_t)kg * N_TOT + n0 + nB;
  __bf16* dB = b_lds + nB * BSTRIDE + kg;
  const int wr = (wv >> 1) * 64, wc = (wv & 1) * 64;
  const int r15 = lane & 15, kgrp = lane >> 4;
  const int selA = kgrp ^ swz_s(r15);
  const __bf16* aRd = a_lds + (wr + r15) * FBK + selA * 8;
  const __bf16* bRd = b_lds + (wc + r15) * BSTRIDE + kgrp * 8;
  f32x4 acc[4][4];
  #pragma unroll
  for (int i = 0; i < 4; ++i)
    #pragma unroll
    for (int j = 0; j < 4; ++j) acc[i][j] = {0.f, 0.f, 0.f, 0.f};
  for (int kt = 0; kt < K_TOT / FBK; ++kt) {
    f32x4 a0lo = *(const f32x4*)(pA0), a0hi = *(const f32x4*)(pA0 + 4);
    f32x4 a1lo = *(const f32x4*)(pA1), a1hi = *(const f32x4*)(pA1 + 4);
    pA0 += FBK; pA1 += FBK;
    bf16x8 a0, a1;
    #pragma unroll
    for (int i = 0; i < 4; ++i) {
      a0[i] = (__bf16)a0lo[i]; a0[i + 4] = (__bf16)a0hi[i];
      a1[i] = (__bf16)a1lo[i]; a1[i + 4] = (__bf16)a1hi[i];
    }
    int qv[16];
    #pragma unroll
    for (int i = 0; i < 16; ++i) qv[i] = pQ[(size_t)i * N_TOT];
    pQ += (size_t)FBK * N_TOT;
    bf16x8 v0, v1;
    #pragma unroll
    for (int i = 0; i < 8; ++i) { v0[i] = (__bf16)(float)qv[i]; v1[i] = (__bf16)(float)qv[i + 8]; }
    *(bf16x8*)dA0 = a0; *(bf16x8*)dA1 = a1;
    *(bf16x8*)(dB) = v0; *(bf16x8*)(dB + 8) = v1;
    __syncthreads();
    bf16x8 af[4], bfr[4];
    #pragma unroll
    for (int mi = 0; mi < 4; ++mi) af[mi] = *(const bf16x8*)(aRd + mi * 16 * FBK);
    #pragma unroll
    for (int ni = 0; ni < 4; ++ni) bfr[ni] = *(const bf16x8*)(bRd + ni * 16 * BSTRIDE);
    #pragma unroll
    for (int mi = 0; mi < 4; ++mi)
      #pragma unroll
      for (int ni = 0; ni < 4; ++ni)
        acc[mi][ni] = __builtin_amdgcn_mfma_f32_16x16x32_bf16(af[mi], bfr[ni], acc[mi][ni], 0, 0, 0);
    __syncthreads();
  }
  const int colb = n0 + wc + r15, rowb = m0 + wr + kgrp * 4;
  #pragma unroll
  for (int ni = 0; ni < 4; ++ni) {
    const int col = colb + ni * 16;
    const float sc = S[col], bb = Bias[col];
    #pragma unroll
    for (int mi = 0; mi < 4; ++mi) {
      const int row = rowb + mi * 16;
      f32x4 a = acc[mi][ni];
      #pragma unroll
      for (int j = 0; j < 4; ++j)
        O[(size_t)(row + j) * N_TOT + col] = a[j] * sc + bb;
    }
  }
}

extern "C" void kernel_launch(void* const* d_in, const int* in_sizes, int n_in,
                              void* d_out, int out_size, void* d_ws, size_t ws_size,
                              hipStream_t stream) {
  const float* A    = (const float*)d_in[0];
  const int*   Q    = (const int*)d_in[1];
  const float* S    = (const float*)d_in[2];
  const float* Bias = (const float*)d_in[3];
  float*       O    = (float*)d_out;

  const size_t A_BYTES = (size_t)M_TOT * K_TOT * 2;   // 64 MiB
  const size_t B_BYTES = (size_t)N_TOT * K_TOT * 2;   // 128 MiB
  const int    LDS_BYTES = 5 * SLOT_ELEMS * 2;        // 163840 (A:3 + B:2)

  if (ws_size >= A_BYTES + B_BYTES) {
    (void)hipFuncSetAttribute((const void*)&w8a16_gemm_ws,
                              hipFuncAttributeMaxDynamicSharedMemorySize,
                              LDS_BYTES);
    __bf16* Abf = (__bf16*)d_ws;
    __bf16* Bt  = (__bf16*)((char*)d_ws + A_BYTES);
    prep_kernel<<<dim3(32768), dim3(256), 0, stream>>>(A, Abf, Q, Bt);
    // GEMM: 32*64 = 2048 blocks, 512 threads, 160 KB dynamic LDS
    w8a16_gemm_ws<<<dim3(2048), dim3(512), LDS_BYTES, stream>>>(Abf, Bt, S, Bias, O);
  } else {
    w8a16_gemm_fused<<<dim3(8192), dim3(256), 0, stream>>>(A, Q, S, Bias, O);
  }
}

// Round 19
// 1146.858 us; speedup vs baseline: 1.0979x; 1.0979x over previous
//
#include <hip/hip_runtime.h>
#include <stdint.h>

// W8A16 GEMM: out[m,n] = s[n] * sum_k a[m,k] * q_int8[k,n] + bias[n]
// M=8192, N=16384, K=4096. Harness dtypes: A,S,Bias f32; Q int32; OUT f32.
//
// Round 19: bit-exact revert to R15 (best measured: 1151 us total;
// GEMM ~1070 us / ~1030 TF / MfmaUtil 48% / 0 bank conflicts).
// R16 (A-prefetch), R17 (32x32 MFMA), R18 (layout) all regressed with a
// shared un-modeled +4cyc/ds_read LDS tax or broken coalescing; the
// verified-win set {pre-pass dequant, 256^2 BK=64 8-wave, A:3+B:2 counted
// vmcnt(4) ring, B-frags-read-one-tile-ahead, merged coalesced prep} is
// exactly this kernel.

typedef __bf16 bf16x8 __attribute__((ext_vector_type(8)));
typedef float  f32x4  __attribute__((ext_vector_type(4)));

#define M_TOT 8192
#define N_TOT 16384
#define K_TOT 4096
#define BM 256
#define BN 256
#define BK 64
#define NT (K_TOT / BK)        // 64 K-tiles (even -> clean 2x unroll)
#define SLOT_ELEMS 16384       // 256 rows * 64 cols bf16 = 32 KB per slot

__device__ __forceinline__ void gload_lds16(const void* g, void* l) {
  __builtin_amdgcn_global_load_lds(
      (const __attribute__((address_space(1))) unsigned int*)g,
      (__attribute__((address_space(3))) unsigned int*)l,
      16, 0, 0);
}

// ---------- merged pre-pass: blocks [0,16384) cvt A; [16384,32768) transpose Q
__global__ void __launch_bounds__(256)
prep_kernel(const float* __restrict__ A, __bf16* __restrict__ Abf,
            const int* __restrict__ Q, __bf16* __restrict__ Bt) {
  __shared__ __bf16 t[64][72];   // 16B-aligned rows (144B); reads 2-way
  const int tid = threadIdx.x;
  if (blockIdx.x < 16384) {
    // ---- A f32 -> bf16, 8 elems/thread, fully coalesced ----
    const size_t i = ((size_t)blockIdx.x * 256 + tid) * 8;
    f32x4 lo = *(const f32x4*)(A + i);
    f32x4 hi = *(const f32x4*)(A + i + 4);
    bf16x8 v;
    #pragma unroll
    for (int j = 0; j < 4; ++j) {
      v[j]     = (__bf16)lo[j];
      v[j + 4] = (__bf16)hi[j];
    }
    *(bf16x8*)(Abf + i) = v;
  } else {
    // ---- Q [K][N] int32 -> Bt [N][K] bf16, 64x64 tile via LDS ----
    const int bid = blockIdx.x - 16384;
    const int bk = bid & 63;             // 64 k-tiles
    const int bn = bid >> 6;             // 256 n-tiles
    const int k0 = bk * 64, n0 = bn * 64;
    const int tx = tid & 63;             // n within tile
    const int ty = tid >> 6;             // k-chunk of 16
    const int kb = ty * 16;
    int q[16];
    #pragma unroll
    for (int i = 0; i < 16; ++i)
      q[i] = Q[(size_t)(k0 + kb + i) * N_TOT + n0 + tx];
    bf16x8 v0, v1;
    #pragma unroll
    for (int i = 0; i < 8; ++i) {
      v0[i] = (__bf16)(float)q[i];
      v1[i] = (__bf16)(float)q[i + 8];
    }
    *(bf16x8*)&t[tx][kb]     = v0;       // t[n][k] = Q[k0+k][n0+n]
    *(bf16x8*)&t[tx][kb + 8] = v1;
    __syncthreads();
    // output: thread j -> row j>>2, k-chunk j&3; lanes 0-3 = 128B contiguous
    const int nrow = tid >> 2;
    const int kc   = (tid & 3) * 16;
    bf16x8 w0 = *(const bf16x8*)&t[nrow][kc];
    bf16x8 w1 = *(const bf16x8*)&t[nrow][kc + 8];
    __bf16* dst = Bt + (size_t)(n0 + nrow) * K_TOT + k0 + kc;
    *(bf16x8*)(dst)     = w0;
    *(bf16x8*)(dst + 8) = w1;
  }
}

// --- main GEMM: 256^2 / BK=64 / A3+B2 ring / B-next-frags-in-regs --------
__global__ void __launch_bounds__(512, 2)
w8a16_gemm_ws(const __bf16* __restrict__ A,   // [M,K] bf16
              const __bf16* __restrict__ Bt,  // [N,K] bf16
              const float*  __restrict__ S,
              const float*  __restrict__ Bias,
              float*        __restrict__ O)
{
  extern __shared__ __bf16 lds[];
  __bf16* const aBase = lds;                     // A: 3 slots of 32 KB
  __bf16* const bBase = lds + 3 * SLOT_ELEMS;    // B: 2 slots of 32 KB

  const int tid  = threadIdx.x;
  const int lane = tid & 63;
  const int wv   = tid >> 6;     // 0..7
  const int wm   = wv >> 2;      // 0..1 : M-wave (rows wm*128)
  const int wn   = wv & 3;       // 0..3 : N-wave (cols wn*64)
  const int rot  = (wv >> 2) << 1;   // SIMD-mates (wv, wv+4) 2 quadrants apart

  // XCD map: xcd owns 8 bx-columns; by fastest (B-panel L2-resident).
  const int bid = blockIdx.x;
  const int xcd = bid & 7;
  const int c   = bid >> 3;                 // [0,256)
  const int bx  = xcd * 8 + (c >> 5);       // [0,64)
  const int by  = c & 31;                   // [0,32)
  const int m0  = by * BM;
  const int n0  = bx * BN;

  // ---- staging geometry (R6-verified, 0 bank conflicts) ----
  const int rr   = tid >> 3;                       // 0..63
  const int cswz = (tid & 7) ^ (rr & 7);
  const __bf16* pa0 = A  + (size_t)(m0 + 0   + rr) * K_TOT + cswz * 8;
  const __bf16* pa1 = A  + (size_t)(m0 + 64  + rr) * K_TOT + cswz * 8;
  const __bf16* pa2 = A  + (size_t)(m0 + 128 + rr) * K_TOT + cswz * 8;
  const __bf16* pa3 = A  + (size_t)(m0 + 192 + rr) * K_TOT + cswz * 8;
  const __bf16* pb0 = Bt + (size_t)(n0 + 0   + rr) * K_TOT + cswz * 8;
  const __bf16* pb1 = Bt + (size_t)(n0 + 64  + rr) * K_TOT + cswz * 8;
  const __bf16* pb2 = Bt + (size_t)(n0 + 128 + rr) * K_TOT + cswz * 8;
  const __bf16* pb3 = Bt + (size_t)(n0 + 192 + rr) * K_TOT + cswz * 8;
  const int dA = tid * 8;

#define STAGE_A(dst) do {                                  \
    gload_lds16(pa0, (dst) + dA);                          \
    gload_lds16(pa1, (dst) + 4096  + dA);                  \
    gload_lds16(pa2, (dst) + 8192  + dA);                  \
    gload_lds16(pa3, (dst) + 12288 + dA);                  \
    pa0 += BK; pa1 += BK; pa2 += BK; pa3 += BK;            \
  } while (0)
#define STAGE_B(dst) do {                                  \
    gload_lds16(pb0, (dst) + dA);                          \
    gload_lds16(pb1, (dst) + 4096  + dA);                  \
    gload_lds16(pb2, (dst) + 8192  + dA);                  \
    gload_lds16(pb3, (dst) + 12288 + dA);                  \
    pb0 += BK; pb1 += BK; pb2 += BK; pb3 += BK;            \
  } while (0)

  // ---- fragment-read constants ----
  const int l15     = lane & 15;
  const int quad    = lane >> 4;
  const int physA0  = quad ^ (l15 & 7);
  const int bRowOff = (wn * 64 + l15) * 64;    // + ni*1024

  f32x4 acc[8][4];   // acc[2*pp+i][ni] <-> quadrant (pp+rot)&3, row pair i
  #pragma unroll
  for (int i = 0; i < 8; ++i)
    #pragma unroll
    for (int j = 0; j < 4; ++j)
      acc[i][j] = {0.f, 0.f, 0.f, 0.f};

  bf16x8 b0[4][2], b1[4][2];   // B frag double-buffer (swap by name)

  // ---- prologue: A(0)->s0, B(0)->bs0, B(1)->bs1, A(1)->s1 ----
  STAGE_A(aBase);
  STAGE_B(bBase);
  STAGE_B(bBase + SLOT_ELEMS);
  STAGE_A(aBase + SLOT_ELEMS);
  asm volatile("s_waitcnt vmcnt(4)" ::: "memory");
  __builtin_amdgcn_s_barrier();

  // peel: B(0) frags -> b0 (from bslot0); drain reads before anyone stages.
  #pragma unroll
  for (int ni = 0; ni < 4; ++ni)
    #pragma unroll
    for (int ks = 0; ks < 2; ++ks)
      b0[ni][ks] = *(const bf16x8*)(
          bBase + bRowOff + ni * 1024 + (physA0 ^ (ks << 2)) * 8);
  asm volatile("s_waitcnt lgkmcnt(0)" ::: "memory");
  __builtin_amdgcn_s_barrier();

  int csA = 0;
  int nsA = 2;

  // TILE body: BCUR = frags of B(t) (in regs), BNXT <- frags of B(t+1)
  // (read from bReadLds during this tile). bStageLds <- DMA dest of B(t+2).
  // Stage issue order per tile: B first (pp0), A second (pp1) -> vmcnt(4)
  // at tile top keeps newest 4 = A(t+1), retires B(t+1).
#define TILE_BODY(t, BCUR, BNXT, bStageLds, bReadLds) do {                  \
    if ((t) < NT - 1) { asm volatile("s_waitcnt vmcnt(4)" ::: "memory"); }  \
    else              { asm volatile("s_waitcnt vmcnt(0)" ::: "memory"); }  \
    asm volatile("s_waitcnt lgkmcnt(0)" ::: "memory");                      \
    __builtin_amdgcn_s_barrier();                                           \
    const __bf16* const aC_ = aBase + csA * SLOT_ELEMS;                     \
    __bf16* const aN_ = aBase + nsA * SLOT_ELEMS;                           \
    _Pragma("unroll")                                                       \
    for (int pp = 0; pp < 4; ++pp) {                                        \
      const int qq = (pp + rot) & 3;                                        \
      const __bf16* aQ = aC_ + (wm * 128 + qq * 32 + l15) * 64;             \
      bf16x8 aA[2][2];                                                      \
      _Pragma("unroll")                                                     \
      for (int i = 0; i < 2; ++i)                                           \
        _Pragma("unroll")                                                   \
        for (int ks = 0; ks < 2; ++ks)                                      \
          aA[i][ks] = *(const bf16x8*)(                                     \
              aQ + i * 1024 + (physA0 ^ (ks << 2)) * 8);                    \
      if ((t) + 1 < NT) {                                                   \
        BNXT[pp][0] = *(const bf16x8*)(                                     \
            (bReadLds) + bRowOff + pp * 1024 + physA0 * 8);                 \
        BNXT[pp][1] = *(const bf16x8*)(                                     \
            (bReadLds) + bRowOff + pp * 1024 + (physA0 ^ 4) * 8);           \
      }                                                                     \
      if (pp == 0 && (t) + 2 < NT) STAGE_B(bStageLds);                      \
      if (pp == 1 && (t) + 2 < NT) STAGE_A(aN_);                            \
      __builtin_amdgcn_s_setprio(1);                                        \
      _Pragma("unroll")                                                     \
      for (int i = 0; i < 2; ++i)                                           \
        _Pragma("unroll")                                                   \
        for (int ni = 0; ni < 4; ++ni)                                      \
          _Pragma("unroll")                                                 \
          for (int ks = 0; ks < 2; ++ks)                                    \
            acc[2 * pp + i][ni] = __builtin_amdgcn_mfma_f32_16x16x32_bf16(  \
                aA[i][ks], BCUR[ni][ks], acc[2 * pp + i][ni], 0, 0, 0);     \
      __builtin_amdgcn_s_setprio(0);                                        \
    }                                                                       \
    csA = (csA == 2) ? 0 : csA + 1;                                         \
    nsA = (nsA == 2) ? 0 : nsA + 1;                                         \
  } while (0)

  for (int tt = 0; tt < NT; tt += 2) {
    // even tile: cur=b0, next->b1; B(t+2) DMA -> slot0, B(t+1) read <- slot1
    TILE_BODY(tt,     b0, b1, bBase,              bBase + SLOT_ELEMS);
    // odd tile: roles swap
    TILE_BODY(tt + 1, b1, b0, bBase + SLOT_ELEMS, bBase);
  }
#undef TILE_BODY
#undef STAGE_A
#undef STAGE_B

  // ---- epilogue: scale+bias, f32 stores ----
  // acc[2*pp+i] holds rows qq*32 + i*16 (+ quad*4 + reg), qq=(pp+rot)&3.
  const int colb = n0 + wn * 64 + l15;
  #pragma unroll
  for (int pp = 0; pp < 4; ++pp) {
    const int qq = (pp + rot) & 3;
    const int rowq = m0 + wm * 128 + qq * 32 + quad * 4;
    #pragma unroll
    for (int i = 0; i < 2; ++i) {
      const int rowb = rowq + i * 16;
      #pragma unroll
      for (int ni = 0; ni < 4; ++ni) {
        const int col = colb + ni * 16;
        const float sc = S[col];
        const float bb = Bias[col];
        f32x4 a = acc[2 * pp + i][ni];
        #pragma unroll
        for (int j = 0; j < 4; ++j)
          O[(size_t)(rowb + j) * N_TOT + col] = a[j] * sc + bb;
      }
    }
  }
}

// ---------------- fallback: fused kernel (ws too small) ----------------
#define FBM 128
#define FBN 128
#define FBK 32
#define BSTRIDE 40
__device__ __forceinline__ int swz_s(int row) {
  return (row & 3) ^ ((row >> 2) & 1);
}
__global__ void __launch_bounds__(256)
w8a16_gemm_fused(const float* __restrict__ A, const int* __restrict__ Q,
                 const float* __restrict__ S, const float* __restrict__ Bias,
                 float* __restrict__ O)
{
  __shared__ __bf16 a_lds[FBM * FBK];
  __shared__ __bf16 b_lds[FBN * BSTRIDE];
  const int tid = threadIdx.x, lane = tid & 63, wv = tid >> 6;
  const int bid = blockIdx.x;
  const int swz = (bid & 7) * 1024 + (bid >> 3);
  const int bx = swz >> 6, by = swz & 63;
  const int m0 = by * FBM, n0 = bx * FBN;
  const int mA0 = tid >> 2, mA1 = (256 + tid) >> 2;
  const int kcA = tid & 3;
  const int kp0 = kcA ^ swz_s(mA0), kp1 = kcA ^ swz_s(mA1);
  const float* pA0 = A + (size_t)(m0 + mA0) * K_TOT + kcA * 8;
  const float* pA1 = A + (size_t)(m0 + mA1) * K_TOT + kcA * 8;
  __bf16* dA0 = a_lds + mA0 * FBK + kp0 * 8;
  __bf16* dA1 = a_lds + mA1 * FBK + kp1 * 8;
  const int nB = tid & 127, kg = (tid >> 7) * 16;
  const int* pQ = Q + (size_t)kg * N_TOT + n0 + nB;
  __bf16* dB = b_lds + nB * BSTRIDE + kg;
  const int wr = (wv >> 1) * 64, wc = (wv & 1) * 64;
  const int r15 = lane & 15, kgrp = lane >> 4;
  const int selA = kgrp ^ swz_s(r15);
  const __bf16* aRd = a_lds + (wr + r15) * FBK + selA * 8;
  const __bf16* bRd = b_lds + (wc + r15) * BSTRIDE + kgrp * 8;
  f32x4 acc[4][4];
  #pragma unroll
  for (int i = 0; i < 4; ++i)
    #pragma unroll
    for (int j = 0; j < 4; ++j) acc[i][j] = {0.f, 0.f, 0.f, 0.f};
  for (int kt = 0; kt < K_TOT / FBK; ++kt) {
    f32x4 a0lo = *(const f32x4*)(pA0), a0hi = *(const f32x4*)(pA0 + 4);
    f32x4 a1lo = *(const f32x4*)(pA1), a1hi = *(const f32x4*)(pA1 + 4);
    pA0 += FBK; pA1 += FBK;
    bf16x8 a0, a1;
    #pragma unroll
    for (int i = 0; i < 4; ++i) {
      a0[i] = (__bf16)a0lo[i]; a0[i + 4] = (__bf16)a0hi[i];
      a1[i] = (__bf16)a1lo[i]; a1[i + 4] = (__bf16)a1hi[i];
    }
    int qv[16];
    #pragma unroll
    for (int i = 0; i < 16; ++i) qv[i] = pQ[(size_t)i * N_TOT];
    pQ += (size_t)FBK * N_TOT;
    bf16x8 v0, v1;
    #pragma unroll
    for (int i = 0; i < 8; ++i) { v0[i] = (__bf16)(float)qv[i]; v1[i] = (__bf16)(float)qv[i + 8]; }
    *(bf16x8*)dA0 = a0; *(bf16x8*)dA1 = a1;
    *(bf16x8*)(dB) = v0; *(bf16x8*)(dB + 8) = v1;
    __syncthreads();
    bf16x8 af[4], bfr[4];
    #pragma unroll
    for (int mi = 0; mi < 4; ++mi) af[mi] = *(const bf16x8*)(aRd + mi * 16 * FBK);
    #pragma unroll
    for (int ni = 0; ni < 4; ++ni) bfr[ni] = *(const bf16x8*)(bRd + ni * 16 * BSTRIDE);
    #pragma unroll
    for (int mi = 0; mi < 4; ++mi)
      #pragma unroll
      for (int ni = 0; ni < 4; ++ni)
        acc[mi][ni] = __builtin_amdgcn_mfma_f32_16x16x32_bf16(af[mi], bfr[ni], acc[mi][ni], 0, 0, 0);
    __syncthreads();
  }
  const int colb = n0 + wc + r15, rowb = m0 + wr + kgrp * 4;
  #pragma unroll
  for (int ni = 0; ni < 4; ++ni) {
    const int col = colb + ni * 16;
    const float sc = S[col], bb = Bias[col];
    #pragma unroll
    for (int mi = 0; mi < 4; ++mi) {
      const int row = rowb + mi * 16;
      f32x4 a = acc[mi][ni];
      #pragma unroll
      for (int j = 0; j < 4; ++j)
        O[(size_t)(row + j) * N_TOT + col] = a[j] * sc + bb;
    }
  }
}

extern "C" void kernel_launch(void* const* d_in, const int* in_sizes, int n_in,
                              void* d_out, int out_size, void* d_ws, size_t ws_size,
                              hipStream_t stream) {
  const float* A    = (const float*)d_in[0];
  const int*   Q    = (const int*)d_in[1];
  const float* S    = (const float*)d_in[2];
  const float* Bias = (const float*)d_in[3];
  float*       O    = (float*)d_out;

  const size_t A_BYTES = (size_t)M_TOT * K_TOT * 2;   // 64 MiB
  const size_t B_BYTES = (size_t)N_TOT * K_TOT * 2;   // 128 MiB
  const int    LDS_BYTES = 5 * SLOT_ELEMS * 2;        // 163840 (A:3 + B:2)

  if (ws_size >= A_BYTES + B_BYTES) {
    (void)hipFuncSetAttribute((const void*)&w8a16_gemm_ws,
                              hipFuncAttributeMaxDynamicSharedMemorySize,
                              LDS_BYTES);
    __bf16* Abf = (__bf16*)d_ws;
    __bf16* Bt  = (__bf16*)((char*)d_ws + A_BYTES);
    // merged pre-pass: 16384 cvt blocks + 16384 transpose blocks
    prep_kernel<<<dim3(32768), dim3(256), 0, stream>>>(A, Abf, Q, Bt);
    // GEMM: 32*64 = 2048 blocks, 512 threads, 160 KB dynamic LDS
    w8a16_gemm_ws<<<dim3(2048), dim3(512), LDS_BYTES, stream>>>(Abf, Bt, S, Bias, O);
  } else {
    w8a16_gemm_fused<<<dim3(8192), dim3(256), 0, stream>>>(A, Q, S, Bias, O);
  }
}